// Round 8
// baseline (553.745 us; speedup 1.0000x reference)
//
#include <hip/hip_runtime.h>
#include <hip/hip_bf16.h>

typedef __attribute__((ext_vector_type(8))) __bf16 bf16x8;
typedef __attribute__((ext_vector_type(4))) __bf16 bf16x4;
typedef __attribute__((ext_vector_type(4))) float f32x4;

#define MFMA16(a,b,c) __builtin_amdgcn_mfma_f32_16x16x32_bf16(a,b,c,0,0,0)

__device__ __forceinline__ void gload_lds16(const void* g, void* l) {
  __builtin_amdgcn_global_load_lds(
      (const __attribute__((address_space(1))) void*)g,
      (__attribute__((address_space(3))) void*)l, 16, 0, 0);
}

__device__ __forceinline__ f32x4 max4(f32x4 a, f32x4 b) {
  f32x4 c;
  c[0] = fmaxf(a[0], b[0]); c[1] = fmaxf(a[1], b[1]);
  c[2] = fmaxf(a[2], b[2]); c[3] = fmaxf(a[3], b[3]);
  return c;
}

// ---------------------------------------------------------------------------
// prep: cast weights to bf16, build padded bf16 bias table [16][64][64]
// ---------------------------------------------------------------------------
__global__ void prep_k(const float* __restrict__ qkv_w, const float* __restrict__ out_w,
                       const float* __restrict__ rpt,
                       __bf16* __restrict__ qwb, __bf16* __restrict__ owb,
                       __bf16* __restrict__ biasb)
{
  int i = blockIdx.x * 256 + threadIdx.x;
  if (i < 786432) { qwb[i] = (__bf16)qkv_w[i]; return; }
  i -= 786432;
  if (i < 262144) { owb[i] = (__bf16)out_w[i]; return; }
  i -= 262144;
  if (i < 65536) {
    int hh = i >> 12, qc = i & 4095, qq = qc >> 6, c = qc & 63;
    __bf16 val;
    if (c >= 49)      val = (__bf16)(-30000.0f);
    else if (qq >= 49) val = (__bf16)(0.0f);
    else {
      int dh = qq / 7 - c / 7 + 6;
      int dw = qq % 7 - c % 7 + 6;
      val = (__bf16)rpt[(dh * 13 + dw) * 16 + hh];
    }
    biasb[i] = val;
  }
}

// ---------------------------------------------------------------------------
// cast hidden_states f32 -> bf16 (8 elems/thread)
// ---------------------------------------------------------------------------
__global__ void cast_k(const float* __restrict__ in, __bf16* __restrict__ outb, int n8)
{
  int i = blockIdx.x * blockDim.x + threadIdx.x;
  int stride = gridDim.x * blockDim.x;
  for (; i < n8; i += stride) {
    const float4* p = (const float4*)in + (size_t)i * 2;
    float4 x = p[0], y = p[1];
    bf16x8 o;
    o[0] = (__bf16)x.x; o[1] = (__bf16)x.y; o[2] = (__bf16)x.z; o[3] = (__bf16)x.w;
    o[4] = (__bf16)y.x; o[5] = (__bf16)y.y; o[6] = (__bf16)y.z; o[7] = (__bf16)y.w;
    ((bf16x8*)outb)[i] = o;
  }
}

// ---------------------------------------------------------------------------
// Register-pipelined 128x128 GEMM, BK=64, 4 waves (2x2, 64x64/wave),
// 64KB LDS -> 2 independent blocks/CU. Per K-tile: 2 k-phases of 16 MFMA;
// operand sets set0/set1 double-buffered in REGISTERS so ds_reads for the
// next phase drain under the current MFMA cluster (counted lgkmcnt(8)).
// ONE barrier per K-tile. T2 swizzle (pre-swizzled global src + XOR ds_read).
// Staging 1-tile-deep: vmcnt(0) at the barrier point waits a prefetch issued
// one full K-tile earlier (~free). Race-free: stage kt+2 -> buf[kt&1] only
// after the barrier at which every wave lgkm(0)-retired its buf[kt&1] reads.
// Swapped MFMA operands (round-7): m = mi*16+r, n = ni*16+g*4+j -> wide stores.
// ---------------------------------------------------------------------------
template<int EPI>
__global__ __launch_bounds__(256, 2)
void gemmrp(const __bf16* __restrict__ A, const __bf16* __restrict__ Bt,
            const float* __restrict__ bvec, float* __restrict__ outp,
            __bf16* __restrict__ qb, __bf16* __restrict__ kb, __bf16* __restrict__ vb,
            int N, int K)
{
  __shared__ __align__(16) char lds[65536];   // 2 bufs x (A 16K + B 16K)
  const int tid = threadIdx.x;
  const int wave = tid >> 6, lane = tid & 63;
  const int g = lane >> 4, r = lane & 15;
  const int l8 = lane >> 3, l7 = lane & 7;
  const int wr = wave >> 1, wc = wave & 1;

  const int ntiles = N >> 7;
  const int nper = gridDim.x >> 3;                       // grid % 8 == 0
  const int b2 = (blockIdx.x & 7) * nper + (blockIdx.x >> 3);  // XCD swizzle
  const int m0 = (b2 / ntiles) << 7;
  const int n0 = (b2 % ntiles) << 7;

  // staging: 4 A + 4 B gloads per thread per K-tile; rows c*32+wave*8+l8,
  // source chunk pre-swizzled (l7^l8), LDS dest linear
  const __bf16* Ag = A + (size_t)(m0 + wave * 8 + l8) * K + (l7 ^ l8) * 8;
  const __bf16* Bg = Bt + (size_t)(n0 + wave * 8 + l8) * K + (l7 ^ l8) * 8;
  const size_t r32 = (size_t)32 * K;
  char* Ald = lds + wave * 1024 + l8 * 128 + l7 * 16;   // + c*4096 (+16384 B) (+cur)

  // ds_read: row*128B + ((chunk)^(r&7))*16B ; ph0 chunks g, ph1 chunks 4+g
  const int ch0 = (g ^ (r & 7)) << 4;
  const int ch1 = ((4 + g) ^ (r & 7)) << 4;
  const int arow = (wr * 64 + r) * 128;          // + mi*2048
  const int brow = 16384 + (wc * 64 + r) * 128;  // + ni*2048

  f32x4 acc[4][4] = {};
  bf16x8 a0[4], b0[4], a1[4], b1[4];             // set0 (k-lo), set1 (k-hi)

#define STAGE_TILE(T)                                                          \
  {                                                                            \
    const __bf16* As_ = Ag + (T) * 64;                                         \
    const __bf16* Bs_ = Bg + (T) * 64;                                         \
    char* Ld_ = lds + (((T) & 1) << 15);                                       \
    _Pragma("unroll")                                                          \
    for (int c = 0; c < 4; ++c) gload_lds16(As_ + c * r32, Ld_ + (Ald - lds) + c * 4096); \
    _Pragma("unroll")                                                          \
    for (int c = 0; c < 4; ++c) gload_lds16(Bs_ + c * r32, Ld_ + (Ald - lds) + 16384 + c * 4096); \
  }

#define READ_SET(AV, BV, T, CH)                                                \
  {                                                                            \
    const char* L_ = lds + (((T) & 1) << 15);                                  \
    _Pragma("unroll")                                                          \
    for (int mi = 0; mi < 4; ++mi) AV[mi] = *(const bf16x8*)(L_ + arow + mi * 2048 + (CH)); \
    _Pragma("unroll")                                                          \
    for (int ni = 0; ni < 4; ++ni) BV[ni] = *(const bf16x8*)(L_ + brow + ni * 2048 + (CH)); \
  }

#define MFMA_SET(AV, BV)                                                       \
  __builtin_amdgcn_s_setprio(1);                                               \
  _Pragma("unroll")                                                            \
  for (int mi = 0; mi < 4; ++mi)                                               \
    _Pragma("unroll")                                                          \
    for (int ni = 0; ni < 4; ++ni)                                             \
      acc[mi][ni] = MFMA16(BV[ni], AV[mi], acc[mi][ni]);                       \
  __builtin_amdgcn_s_setprio(0);

  // prologue: stage tiles 0,1; load set0/set1 for tile 0
  STAGE_TILE(0);
  STAGE_TILE(1);
  asm volatile("s_waitcnt vmcnt(8)" ::: "memory");   // tile 0 (my oldest 8) landed
  __builtin_amdgcn_s_barrier();                      // collective: tile 0 ready
  READ_SET(a0, b0, 0, ch0);
  READ_SET(a1, b1, 0, ch1);
  asm volatile("s_waitcnt lgkmcnt(8)" ::: "memory"); // set0 done, set1 in flight

  const int nkt = K >> 6;                            // 8
#pragma unroll 1
  for (int kt = 0; kt < nkt; ++kt) {
    // A: MFMA k-lo (set0 ready; set1 reads drain underneath)
    MFMA_SET(a0, b0);
    // B: sync point — my buf[kt&1] reads all retired; tile kt+1 staged
    asm volatile("s_waitcnt lgkmcnt(0)" ::: "memory");
    asm volatile("s_waitcnt vmcnt(0)" ::: "memory");
    __builtin_amdgcn_s_barrier();
    // C: stage tile kt+2 into buf[kt&1]; read (kt+1, k-lo) -> set0
    if (kt + 2 < nkt) STAGE_TILE(kt + 2);
    if (kt + 1 < nkt) READ_SET(a0, b0, kt + 1, ch0);
    // D: MFMA k-hi (set1 ready; set0 reads drain underneath)
    MFMA_SET(a1, b1);
    // E: read (kt+1, k-hi) -> set1; wait older 8 (set0) only
    if (kt + 1 < nkt) {
      READ_SET(a1, b1, kt + 1, ch1);
      asm volatile("s_waitcnt lgkmcnt(8)" ::: "memory");
    }
  }

  // bias vectors, 16B-aligned
  f32x4 bv4[4];
#pragma unroll
  for (int ni = 0; ni < 4; ++ni)
    bv4[ni] = *(const f32x4*)(bvec + n0 + wc * 64 + ni * 16 + g * 4);

  if (EPI == 1) {
#pragma unroll
    for (int mi = 0; mi < 4; ++mi) {
      int row = m0 + wr * 64 + mi * 16 + r;
      float* orow = outp + (size_t)row * N + n0 + wc * 64 + g * 4;
#pragma unroll
      for (int ni = 0; ni < 4; ++ni) {
        f32x4 w = acc[mi][ni] + bv4[ni];
        *(f32x4*)(orow + ni * 16) = w;
      }
    }
  } else {
    __bf16* dst; float scl;
    const int which = n0 >> 9;
    if (which == 0)      { dst = qb; scl = 0.17677669529663687f; }
    else if (which == 1) { dst = kb; scl = 1.0f; }
    else                 { dst = vb; scl = 1.0f; }
    int hh_[4], d0_[4];
#pragma unroll
    for (int ni = 0; ni < 4; ++ni) {
      int nl = (n0 + wc * 64 + ni * 16) & 511;
      hh_[ni] = nl >> 5;
      d0_[ni] = (nl & 31) + g * 4;
    }
#pragma unroll
    for (int mi = 0; mi < 4; ++mi) {
      int m = m0 + wr * 64 + mi * 16 + r;
      int bb = m / 49, t = m - bb * 49;
      __bf16* dr = dst + (size_t)bb * 25088 + t * 32;
#pragma unroll
      for (int ni = 0; ni < 4; ++ni) {
        f32x4 v = acc[mi][ni];
        bf16x4 w;
#pragma unroll
        for (int j = 0; j < 4; ++j) w[j] = (__bf16)((v[j] + bv4[ni][j]) * scl);
        *(bf16x4*)(dr + hh_[ni] * 1568 + d0_[ni]) = w;
      }
    }
  }
#undef STAGE_TILE
#undef READ_SET
#undef MFMA_SET
}

// ---------------------------------------------------------------------------
// Attention: 4 waves/block = 4 heads of one b (unchanged from round 2).
// ---------------------------------------------------------------------------
__global__ __launch_bounds__(256, 4)
void attn_k(const __bf16* __restrict__ qb, const __bf16* __restrict__ kb,
            const __bf16* __restrict__ vb, const __bf16* __restrict__ bias_p,
            const float* __restrict__ mask, __bf16* __restrict__ ao)
{
  __shared__ float maskl[64 * 64];
  __shared__ __bf16 Vt[4][32 * 64];
  __shared__ __bf16 Pl[4][16 * 64];
  const int tid = threadIdx.x, wave = tid >> 6, lane = tid & 63;
  const int g = lane >> 4, r = lane & 15;
  const int b = blockIdx.x >> 2, hg = blockIdx.x & 3;
  const int h = hg * 4 + wave;
  const size_t bh = (size_t)b * 16 + h;
  const __bf16* q = qb + bh * 1568;
  const __bf16* k = kb + bh * 1568;
  const __bf16* v = vb + bh * 1568;
  const bf16x8 z8 = {};
  const f32x4 z4 = {};

  bf16x8* vtz = (bf16x8*)Vt[wave];
#pragma unroll
  for (int i = 0; i < 4; ++i) vtz[i * 64 + lane] = z8;

  const float* mb = mask + (size_t)b * 2401;
#pragma unroll
  for (int i = 0; i < 16; ++i) {
    int idx = i * 256 + tid;
    int qq = idx >> 6, c = idx & 63;
    float mv = (qq < 49 && c < 49) ? mb[qq * 49 + c] : 0.0f;
    maskl[qq * 64 + (c ^ ((qq & 7) << 2))] = mv;
  }

  bf16x8 kf[4], qf[4];
#pragma unroll
  for (int i = 0; i < 4; ++i) {
    int row = i * 16 + r;
    kf[i] = (row < 49) ? *(const bf16x8*)(k + row * 32 + g * 8) : z8;
    qf[i] = (row < 49) ? *(const bf16x8*)(q + row * 32 + g * 8) : z8;
  }

  __syncthreads();

  char* vt = (char*)Vt[wave];
#pragma unroll
  for (int i = 0; i < 4; ++i) {
    int idx = i * 64 + lane;
    int t = idx >> 2, d0 = (idx & 3) << 3;
    if (t < 49) {
      bf16x8 vv = *(const bf16x8*)(v + t * 32 + d0);
#pragma unroll
      for (int j = 0; j < 8; ++j) {
        int d = d0 + j;
        *(__bf16*)(vt + d * 128 + ((t * 2) ^ ((d & 7) << 4))) = vv[j];
      }
    }
  }

  bf16x8 vf[2][2];
#pragma unroll
  for (int di = 0; di < 2; ++di) {
    int row = di * 16 + r;
#pragma unroll
    for (int t = 0; t < 2; ++t)
      vf[di][t] = *(const bf16x8*)(vt + row * 128 + (((t * 32 + g * 8) * 2) ^ ((row & 7) << 4)));
  }

  const __bf16* bp = bias_p + h * 4096;
  char* pw = (char*)Pl[wave];
  __bf16* aob = ao + (size_t)b * 25088 + h * 32;
  const int swz = (r & 7) << 4;
  const int mswz = (r & 7) << 2;

#pragma unroll
  for (int qi = 0; qi < 4; ++qi) {
    f32x4 s[4];
#pragma unroll
    for (int mi = 0; mi < 4; ++mi) s[mi] = MFMA16(kf[mi], qf[qi], z4);

    const int qrow = qi * 16 + r;
#pragma unroll
    for (int mi = 0; mi < 4; ++mi) {
      int c0 = mi * 16 + g * 4;
      bf16x4 b4 = *(const bf16x4*)(bp + qrow * 64 + c0);
      f32x4 m4 = *(const f32x4*)(maskl + qrow * 64 + (c0 ^ mswz));
#pragma unroll
      for (int jj = 0; jj < 4; ++jj)
        s[mi][jj] += (float)b4[jj] + m4[jj];
    }
    f32x4 aa = max4(max4(s[0], s[1]), max4(s[2], s[3]));
    float mx = fmaxf(fmaxf(aa[0], aa[1]), fmaxf(aa[2], aa[3]));
    mx = fmaxf(mx, __shfl_xor(mx, 16));
    mx = fmaxf(mx, __shfl_xor(mx, 32));
    float sum = 0.0f;
#pragma unroll
    for (int mi = 0; mi < 4; ++mi) {
#pragma unroll
      for (int jj = 0; jj < 4; ++jj) {
        float e = __expf(s[mi][jj] - mx);
        s[mi][jj] = e;
        sum += e;
      }
    }
    sum += __shfl_xor(sum, 16);
    sum += __shfl_xor(sum, 32);
    const float rinv = 1.0f / sum;

#pragma unroll
    for (int mi = 0; mi < 4; ++mi) {
      bf16x4 w;
#pragma unroll
      for (int jj = 0; jj < 4; ++jj) w[jj] = (__bf16)(s[mi][jj] * rinv);
      *(bf16x4*)(pw + r * 128 + (((mi * 16 + g * 4) * 2) ^ swz)) = w;
    }
    bf16x8 pa0 = *(const bf16x8*)(pw + r * 128 + ((g * 16) ^ swz));
    bf16x8 pa1 = *(const bf16x8*)(pw + r * 128 + ((64 + g * 16) ^ swz));

#pragma unroll
    for (int di = 0; di < 2; ++di) {
      f32x4 o = MFMA16(pa0, vf[di][0], z4);
      o = MFMA16(pa1, vf[di][1], o);
#pragma unroll
      for (int jj = 0; jj < 4; ++jj) {
        int qq = qi * 16 + g * 4 + jj;
        if (qq < 49)
          aob[(size_t)qq * 512 + di * 16 + r] = (__bf16)o[jj];
      }
    }
  }
}

// ---------------------------------------------------------------------------
extern "C" void kernel_launch(void* const* d_in, const int* in_sizes, int n_in,
                              void* d_out, int out_size, void* d_ws, size_t ws_size,
                              hipStream_t stream)
{
  const float* hs    = (const float*)d_in[0];
  const float* mask  = (const float*)d_in[1];
  const float* qkv_w = (const float*)d_in[2];
  const float* qkv_b = (const float*)d_in[3];
  const float* out_w = (const float*)d_in[4];
  const float* out_b = (const float*)d_in[5];
  const float* rpt   = (const float*)d_in[6];
  float* out = (float*)d_out;

  char* ws = (char*)d_ws;
  __bf16* hsb  = (__bf16*)(ws);                  // reused as attn-out after GEMM1
  __bf16* qb   = (__bf16*)(ws + 102760448);
  __bf16* kb   = (__bf16*)(ws + 205520896);
  __bf16* vb   = (__bf16*)(ws + 308281344);
  __bf16* qwb  = (__bf16*)(ws + 411041792);
  __bf16* owb  = (__bf16*)(ws + 412614656);
  __bf16* biasb= (__bf16*)(ws + 413138944);      // [16][64][64] bf16

  prep_k<<<4352, 256, 0, stream>>>(qkv_w, out_w, rpt, qwb, owb, biasb);
  cast_k<<<2048, 256, 0, stream>>>(hs, hsb, 6422528);
  gemmrp<0><<<9408, 256, 0, stream>>>(hsb, qwb, qkv_b, nullptr, qb, kb, vb,
                                      1536, 512);
  attn_k<<<8192, 256, 0, stream>>>(qb, kb, vb, biasb, mask, hsb);
  gemmrp<1><<<3136, 256, 0, stream>>>(hsb, owb, out_b, out, nullptr, nullptr, nullptr,
                                      512, 512);
}